// Round 1
// baseline (890.162 us; speedup 1.0000x reference)
//
#include <hip/hip_runtime.h>

#define S_LEN 2048
#define B_SZ 2048

// quad_perm broadcast: every lane of each 4-lane quad gets quad-lane K's value
template <int PAT>
__device__ __forceinline__ float qbcast(float v) {
  int r = __builtin_amdgcn_update_dpp(0, __builtin_bit_cast(int, v), PAT, 0xF,
                                      0xF, false);
  return __builtin_bit_cast(float, r);
}

// One LSTM cell step for one layer.
// Lane layout (per 16-lane group = 1 batch elem): G = lane&15 = j*4 + type
// (j = hidden idx, type: 0=i 1=f 2=g 3=o). Each lane computes the raw gate
// for its (type, j) via its private weight row, applies its own nonlinearity
// (kk/mm/dd per-lane consts), quad-broadcasts i,f,g,o within the quad (= one
// hidden unit), updates c_j/h_j redundantly on all 4 quad lanes, then
// row-gathers h_0..h_3 via bpermute for the next layer / next timestep.
__device__ __forceinline__ void lstm_step(float i0, float i1, float i2,
                                          float i3, const float (&wi)[4],
                                          const float (&wh)[4], float bias,
                                          float kk, float mm, float dd, int s0,
                                          int s1, int s2, int s3,
                                          float (&hv)[4], float &c) {
  // gate pre-activation: two parallel FMA chains, depth 5
  float a0 = fmaf(wi[0], i0, bias);
  a0 = fmaf(wi[2], i2, a0);
  a0 = fmaf(wh[0], hv[0], a0);
  a0 = fmaf(wh[2], hv[2], a0);
  float a1 = wi[1] * i1;
  a1 = fmaf(wi[3], i3, a1);
  a1 = fmaf(wh[1], hv[1], a1);
  a1 = fmaf(wh[3], hv[3], a1);
  float a = a0 + a1;
  // per-lane nonlinearity: sigmoid (types i,f,o) or tanh (type g)
  // act = mm / (1 + exp2(kk*a)) + dd
  float e = __builtin_amdgcn_exp2f(a * kk);
  float r = __builtin_amdgcn_rcpf(1.0f + e);
  float act = fmaf(mm, r, dd);
  // gather this hidden unit's 4 activated gates (quad-local!)
  float gi = qbcast<0x00>(act);
  float gf = qbcast<0x55>(act);
  float gg = qbcast<0xAA>(act);
  float go = qbcast<0xFF>(act);
  // cell/hidden update (all 4 quad lanes redundantly compute j's update)
  c = fmaf(gf, c, gi * gg);
  float te = __builtin_amdgcn_exp2f(c * -2.8853900817779268f);  // -2*log2(e)
  float tr = __builtin_amdgcn_rcpf(1.0f + te);
  float th = fmaf(2.0f, tr, -1.0f);  // tanh(c)
  float h = go * th;
  // broadcast h_0..h_3 across the 16-lane row (canonical order)
  hv[0] = __shfl(h, s0);
  hv[1] = __shfl(h, s1);
  hv[2] = __shfl(h, s2);
  hv[3] = __shfl(h, s3);
}

// One pipeline tick. Layer l processes time t = tau - l. Reverse layer order
// so layer l reads layer l-1's h from the PREVIOUS tick before it's updated.
#define TICK(A1, A2, A3, ST, XV0, XV1, TAU)                                    \
  do {                                                                         \
    if (A3) {                                                                  \
      lstm_step(h2v[0], h2v[1], h2v[2], h2v[3], wi3, wh3, bia3, kk, mm, dd,    \
                s0, s1, s2, s3, h3v, c3);                                      \
      if (ST) {                                                                \
        float y = fmaf(wo[0], h3v[0],                                          \
                       fmaf(wo[1], h3v[1],                                     \
                            fmaf(wo[2], h3v[2], fmaf(wo[3], h3v[3], bo))));    \
        if (G == 0) out[(TAU - 3) * B_SZ + bidx] = y;                          \
      }                                                                        \
    }                                                                          \
    if (A2)                                                                    \
      lstm_step(h1v[0], h1v[1], h1v[2], h1v[3], wi2, wh2, bia2, kk, mm, dd,    \
                s0, s1, s2, s3, h2v, c2);                                      \
    if (A1)                                                                    \
      lstm_step(h0v[0], h0v[1], h0v[2], h0v[3], wi1, wh1, bia1, kk, mm, dd,    \
                s0, s1, s2, s3, h1v, c1);                                      \
    lstm_step(XV0, XV1, 0.0f, 0.0f, wi0, wh0, bia0, kk, mm, dd, s0, s1, s2,    \
              s3, h0v, c0);                                                    \
  } while (0)

__global__ void __launch_bounds__(64, 1)
    lstm_kernel(const float *__restrict__ x, const float *__restrict__ Wih0,
                const float *__restrict__ Whh0, const float *__restrict__ bih0,
                const float *__restrict__ bhh0, const float *__restrict__ Wihr,
                const float *__restrict__ Whhr, const float *__restrict__ bihr,
                const float *__restrict__ bhhr, const float *__restrict__ Wout,
                const float *__restrict__ bout, float *__restrict__ out) {
  const int lane = threadIdx.x & 63;
  const int G = lane & 15;   // gate slot within batch group: j*4 + type
  const int ty = G & 3;      // gate type: 0=i 1=f 2=g 3=o
  const int bidx = blockIdx.x * 4 + (lane >> 4);  // batch element
  const int row = ty * 4 + (G >> 2);  // PyTorch weight row = type*H + j

  // ---- per-lane weight rows (registers) ----
  float wi0[4], wh0[4], wi1[4], wh1[4], wi2[4], wh2[4], wi3[4], wh3[4];
  wi0[0] = Wih0[row * 2 + 0];
  wi0[1] = Wih0[row * 2 + 1];
  wi0[2] = 0.0f;
  wi0[3] = 0.0f;
#pragma unroll
  for (int k = 0; k < 4; ++k) {
    wh0[k] = Whh0[row * 4 + k];
    wi1[k] = Wihr[0 * 64 + row * 4 + k];
    wh1[k] = Whhr[0 * 64 + row * 4 + k];
    wi2[k] = Wihr[1 * 64 + row * 4 + k];
    wh2[k] = Whhr[1 * 64 + row * 4 + k];
    wi3[k] = Wihr[2 * 64 + row * 4 + k];
    wh3[k] = Whhr[2 * 64 + row * 4 + k];
  }
  const float bia0 = bih0[row] + bhh0[row];
  const float bia1 = bihr[0 * 16 + row] + bhhr[0 * 16 + row];
  const float bia2 = bihr[1 * 16 + row] + bhhr[1 * 16 + row];
  const float bia3 = bihr[2 * 16 + row] + bhhr[2 * 16 + row];
  float wo[4];
#pragma unroll
  for (int k = 0; k < 4; ++k) wo[k] = Wout[k];
  const float bo = bout[0];

  // per-lane activation constants: sigmoid for i,f,o; tanh for g
  const float L2E = 1.4426950408889634f;
  const float kk = (ty == 2) ? -2.0f * L2E : -L2E;
  const float mm = (ty == 2) ? 2.0f : 1.0f;
  const float dd = (ty == 2) ? -1.0f : 0.0f;

  // bpermute source lanes for the h row-broadcast (quad k's lane 0)
  const int rb = lane & 48;
  const int s0 = rb, s1 = rb + 4, s2 = rb + 8, s3 = rb + 12;

  // ---- recurrent state ----
  float h0v[4] = {0, 0, 0, 0}, h1v[4] = {0, 0, 0, 0}, h2v[4] = {0, 0, 0, 0},
        h3v[4] = {0, 0, 0, 0};
  float c0 = 0, c1 = 0, c2 = 0, c3 = 0;

  const float2 *__restrict__ px = (const float2 *)x;  // [S*B] float2 (IN=2)

  // ---- warm-up: fill the 4-deep layer pipeline (ticks 0..2) ----
  {
    float2 xv = px[0 * B_SZ + bidx];
    TICK(false, false, false, false, xv.x, xv.y, 0);
    xv = px[1 * B_SZ + bidx];
    TICK(true, false, false, false, xv.x, xv.y, 1);
    xv = px[2 * B_SZ + bidx];
    TICK(true, true, false, false, xv.x, xv.y, 2);
  }

  // ---- x prefetch buffer: 8 ticks ahead ----
  float2 xq[8];
#pragma unroll
  for (int u = 0; u < 8; ++u) xq[u] = px[(3 + u) * B_SZ + bidx];

  // ---- main loop: ticks 3..2050 (2048 ticks = 256 x 8) ----
  for (int it = 0; it < 256; ++it) {
    const int tau0 = 3 + it * 8;
#pragma unroll
    for (int u = 0; u < 8; ++u) {
      const int tau = tau0 + u;
      float2 xv = xq[u];
      int tn = tau + 8;  // prefetch for next chunk (clamped; drain reads junk
      if (tn > S_LEN - 1) tn = S_LEN - 1;  // that never reaches a stored y)
      xq[u] = px[tn * B_SZ + bidx];
      TICK(true, true, true, true, xv.x, xv.y, tau);
    }
  }
}

extern "C" void kernel_launch(void *const *d_in, const int *in_sizes, int n_in,
                              void *d_out, int out_size, void *d_ws,
                              size_t ws_size, hipStream_t stream) {
  (void)in_sizes;
  (void)n_in;
  (void)out_size;
  (void)d_ws;
  (void)ws_size;
  const float *x = (const float *)d_in[0];
  const float *Wih0 = (const float *)d_in[1];
  const float *Whh0 = (const float *)d_in[2];
  const float *bih0 = (const float *)d_in[3];
  const float *bhh0 = (const float *)d_in[4];
  const float *Wihr = (const float *)d_in[5];
  const float *Whhr = (const float *)d_in[6];
  const float *bihr = (const float *)d_in[7];
  const float *bhhr = (const float *)d_in[8];
  const float *Wout = (const float *)d_in[9];
  const float *bout = (const float *)d_in[10];
  lstm_kernel<<<dim3(512), dim3(64), 0, stream>>>(
      x, Wih0, Whh0, bih0, bhh0, Wihr, Whhr, bihr, bhhr, Wout, bout,
      (float *)d_out);
}

// Round 2
// 671.752 us; speedup vs baseline: 1.3251x; 1.3251x over previous
//
#include <hip/hip_runtime.h>

#define S_LEN 2048
#define B_SZ 2048

// Pure-VALU DPP move: lane gets src from pattern CTRL (quad_perm or row_ror).
// No LDS pipe, no lgkmcnt — this is the whole point of this revision.
template <int CTRL>
__device__ __forceinline__ float dppmov(float v) {
  int r = __builtin_amdgcn_update_dpp(0, __builtin_bit_cast(int, v), CTRL, 0xF,
                                      0xF, true);
  return __builtin_bit_cast(float, r);
}

// One LSTM cell step for one layer.
// Lane layout (16-lane group = 1 batch elem): G = lane&15 = j*4 + type
// (j = hidden unit, type 0=i 1=f 2=g 3=o). Each lane computes its gate via a
// private (pre-rotated) weight row, applies its per-lane nonlinearity,
// quad-broadcasts i,f,g,o (quad_perm DPP), updates c_j/h_j redundantly on the
// quad, then distributes h across the row with 3 row_ror DPPs. hv[] is in
// ROTATED order hv[k] = h_{(j + s*k)&3}; all weight rows were pre-rotated with
// the same s at init, so consumers line up.
template <bool IN2>
__device__ __forceinline__ void lstm_step(float i0, float i1, float i2,
                                          float i3, const float (&wi)[4],
                                          const float (&wh)[4], float bias,
                                          float kk, float mm, float dd,
                                          float (&hv)[4], float &c) {
  // gate pre-activation, tree form (depth ~4)
  float a0 = fmaf(wi[1], i1, fmaf(wi[0], i0, bias));
  float a2 = fmaf(wh[1], hv[1], wh[0] * hv[0]);
  float a3 = fmaf(wh[3], hv[3], wh[2] * hv[2]);
  float a;
  if (IN2) {
    a = a0 + (a2 + a3);  // layer 0: only 2 input terms
  } else {
    float a1 = fmaf(wi[3], i3, wi[2] * i2);
    a = (a0 + a1) + (a2 + a3);
  }
  // per-lane nonlinearity: act = mm / (1 + exp2(kk*a)) + dd
  float e = __builtin_amdgcn_exp2f(a * kk);
  float r = __builtin_amdgcn_rcpf(1.0f + e);
  float act = fmaf(mm, r, dd);
  // quad-local gather of this unit's 4 activated gates
  float gi = dppmov<0x00>(act);
  float gf = dppmov<0x55>(act);
  float gg = dppmov<0xAA>(act);
  float go = dppmov<0xFF>(act);
  // cell/hidden update (redundant on all 4 quad lanes)
  c = fmaf(gf, c, gi * gg);
  float te = __builtin_amdgcn_exp2f(c * -2.8853900817779268f);  // -2*log2(e)
  float tr = __builtin_amdgcn_rcpf(1.0f + te);
  float th = fmaf(2.0f, tr, -1.0f);  // tanh(c)
  float h = go * th;
  // distribute h across the 16-lane row: VALU-only row rotates
  hv[0] = h;                   // h_{j}
  hv[1] = dppmov<0x124>(h);    // row_ror:4  -> h_{(j+s)&3}
  hv[2] = dppmov<0x128>(h);    // row_ror:8  -> h_{(j+2)&3}
  hv[3] = dppmov<0x12C>(h);    // row_ror:12 -> h_{(j+3s)&3}
}

// One pipeline tick. Layer l processes time t = tau - l, reverse layer order
// so each layer reads the previous layer's h from the PREVIOUS tick.
#define TICK(A1, A2, A3, ST, XV0, XV1, TAU)                                    \
  do {                                                                         \
    if (A3) {                                                                  \
      lstm_step<false>(h2v[0], h2v[1], h2v[2], h2v[3], wi3, wh3, bia3, kk, mm, \
                       dd, h3v, c3);                                           \
      if (ST) {                                                                \
        float y = fmaf(wo[0], h3v[0],                                          \
                       fmaf(wo[1], h3v[1],                                     \
                            fmaf(wo[2], h3v[2], fmaf(wo[3], h3v[3], bo))));    \
        if (G == 0) out[(TAU - 3) * B_SZ + bidx] = y;                          \
      }                                                                        \
    }                                                                          \
    if (A2)                                                                    \
      lstm_step<false>(h1v[0], h1v[1], h1v[2], h1v[3], wi2, wh2, bia2, kk, mm, \
                       dd, h2v, c2);                                           \
    if (A1)                                                                    \
      lstm_step<false>(h0v[0], h0v[1], h0v[2], h0v[3], wi1, wh1, bia1, kk, mm, \
                       dd, h1v, c1);                                           \
    lstm_step<true>(XV0, XV1, 0.0f, 0.0f, wi0, wh0, bia0, kk, mm, dd, h0v,     \
                    c0);                                                       \
  } while (0)

__global__ void __launch_bounds__(64, 1)
    lstm_kernel(const float *__restrict__ x, const float *__restrict__ Wih0,
                const float *__restrict__ Whh0, const float *__restrict__ bih0,
                const float *__restrict__ bhh0, const float *__restrict__ Wihr,
                const float *__restrict__ Whhr, const float *__restrict__ bihr,
                const float *__restrict__ bhhr, const float *__restrict__ Wout,
                const float *__restrict__ bout, float *__restrict__ out) {
  const int lane = threadIdx.x & 63;
  const int G = lane & 15;            // gate slot: j*4 + type
  const int ty = G & 3;               // gate type: 0=i 1=f 2=g 3=o
  const int j = G >> 2;               // hidden unit owned by this quad
  const int bidx = blockIdx.x * 4 + (lane >> 4);  // batch element
  const int row = ty * 4 + j;         // PyTorch weight row = type*H + j

  // ---- detect ROW_ROR direction (init-only, direction-proof) ----
  // probe: rotate each lane's own quad index by one quad; s = (j_recv - j)&3
  float jf = (float)j;
  float pr = dppmov<0x124>(jf);
  const int s = (((int)pr) - j) & 3;  // 1 or 3 (== -1 mod 4)

  // rotated hidden index for slot k: idx(k) = (j + s*k) & 3
  int idx1 = (j + s) & 3;
  int idx2 = (j + 2) & 3;
  int idx3 = (j + 3 * s) & 3;
  int rix[4] = {j, idx1, idx2, idx3};

  // ---- per-lane weight rows (registers), pre-rotated to match row_ror ----
  float wi0[4], wh0[4], wi1[4], wh1[4], wi2[4], wh2[4], wi3[4], wh3[4];
  wi0[0] = Wih0[row * 2 + 0];
  wi0[1] = Wih0[row * 2 + 1];
  wi0[2] = 0.0f;
  wi0[3] = 0.0f;
#pragma unroll
  for (int k = 0; k < 4; ++k) {
    int rk = rix[k];
    wh0[k] = Whh0[row * 4 + rk];
    wi1[k] = Wihr[0 * 64 + row * 4 + rk];
    wh1[k] = Whhr[0 * 64 + row * 4 + rk];
    wi2[k] = Wihr[1 * 64 + row * 4 + rk];
    wh2[k] = Whhr[1 * 64 + row * 4 + rk];
    wi3[k] = Wihr[2 * 64 + row * 4 + rk];
    wh3[k] = Whhr[2 * 64 + row * 4 + rk];
  }
  const float bia0 = bih0[row] + bhh0[row];
  const float bia1 = bihr[0 * 16 + row] + bhhr[0 * 16 + row];
  const float bia2 = bihr[1 * 16 + row] + bhhr[1 * 16 + row];
  const float bia3 = bihr[2 * 16 + row] + bhhr[2 * 16 + row];
  float wo[4];
#pragma unroll
  for (int k = 0; k < 4; ++k) wo[k] = Wout[rix[k]];
  const float bo = bout[0];

  // per-lane activation constants: sigmoid for i,f,o; tanh for g
  const float L2E = 1.4426950408889634f;
  const float kk = (ty == 2) ? -2.0f * L2E : -L2E;
  const float mm = (ty == 2) ? 2.0f : 1.0f;
  const float dd = (ty == 2) ? -1.0f : 0.0f;

  // ---- recurrent state (hv arrays are in rotated order) ----
  float h0v[4] = {0, 0, 0, 0}, h1v[4] = {0, 0, 0, 0}, h2v[4] = {0, 0, 0, 0},
        h3v[4] = {0, 0, 0, 0};
  float c0 = 0, c1 = 0, c2 = 0, c3 = 0;

  const float2 *__restrict__ px = (const float2 *)x;  // [S*B] float2 (IN=2)

  // ---- warm-up: fill the 4-deep layer pipeline (ticks 0..2) ----
  {
    float2 xv = px[0 * B_SZ + bidx];
    TICK(false, false, false, false, xv.x, xv.y, 0);
    xv = px[1 * B_SZ + bidx];
    TICK(true, false, false, false, xv.x, xv.y, 1);
    xv = px[2 * B_SZ + bidx];
    TICK(true, true, false, false, xv.x, xv.y, 2);
  }

  // ---- x prefetch buffer: 8 ticks ahead ----
  float2 xq[8];
#pragma unroll
  for (int u = 0; u < 8; ++u) xq[u] = px[(3 + u) * B_SZ + bidx];

  // ---- main loop: ticks 3..2050 (2048 ticks = 256 x 8) ----
  for (int it = 0; it < 256; ++it) {
    const int tau0 = 3 + it * 8;
#pragma unroll
    for (int u = 0; u < 8; ++u) {
      const int tau = tau0 + u;
      float2 xv = xq[u];
      int tn = tau + 8;  // prefetch for next chunk (clamped; drain reads junk
      if (tn > S_LEN - 1) tn = S_LEN - 1;  // that never reaches a stored y)
      xq[u] = px[tn * B_SZ + bidx];
      TICK(true, true, true, true, xv.x, xv.y, tau);
    }
  }
}

extern "C" void kernel_launch(void *const *d_in, const int *in_sizes, int n_in,
                              void *d_out, int out_size, void *d_ws,
                              size_t ws_size, hipStream_t stream) {
  (void)in_sizes;
  (void)n_in;
  (void)out_size;
  (void)d_ws;
  (void)ws_size;
  const float *x = (const float *)d_in[0];
  const float *Wih0 = (const float *)d_in[1];
  const float *Whh0 = (const float *)d_in[2];
  const float *bih0 = (const float *)d_in[3];
  const float *bhh0 = (const float *)d_in[4];
  const float *Wihr = (const float *)d_in[5];
  const float *Whhr = (const float *)d_in[6];
  const float *bihr = (const float *)d_in[7];
  const float *bhhr = (const float *)d_in[8];
  const float *Wout = (const float *)d_in[9];
  const float *bout = (const float *)d_in[10];
  lstm_kernel<<<dim3(512), dim3(64), 0, stream>>>(
      x, Wih0, Whh0, bih0, bhh0, Wihr, Whhr, bihr, bhhr, Wout, bout,
      (float *)d_out);
}

// Round 3
// 649.520 us; speedup vs baseline: 1.3705x; 1.0342x over previous
//
#include <hip/hip_runtime.h>

#define S_LEN 2048
#define B_SZ 2048

// Pure-VALU DPP move (no LDS pipe, no lgkmcnt).
template <int CTRL>
__device__ __forceinline__ float dppmov(float v) {
  int r = __builtin_amdgcn_update_dpp(0, __builtin_bit_cast(int, v), CTRL, 0xF,
                                      0xF, true);
  return __builtin_bit_cast(float, r);
}

// Lane layout (16-lane group = 1 batch elem): G = lane&15 = j*4 + ty
// (j = hidden unit, ty 0=i 1=f 2=g 3=o). Weight rows are per-lane registers,
// PRE-SCALED by the lane's activation constant kk, and pre-rotated to match
// the row_ror h distribution (hv[k] = h_{(j+s*k)&3}).
//
// One pipeline tick, all 4 layers INTERLEAVED stage-by-stage (ILP=4 at every
// stage). Layer l processes t = tau - l; all pre-activations read the
// previous tick's hv state (state is rewritten only at the bottom).
#define TICK(A1, A2, A3, ST, XVX, XVY, TAU)                                    \
  do {                                                                         \
    /* ---- stage 1: pre-activations (read OLD hv state) ---- */               \
    float aa0, aa1 = 0.f, aa2 = 0.f, aa3 = 0.f;                                \
    {                                                                          \
      float t0 = fmaf(wi0[1], (XVY), fmaf(wi0[0], (XVX), bia0));               \
      float t2 = fmaf(wh0[1], h0v[1], wh0[0] * h0v[0]);                        \
      float t3 = fmaf(wh0[3], h0v[3], wh0[2] * h0v[2]);                        \
      aa0 = t0 + (t2 + t3);                                                    \
    }                                                                          \
    if (A1) {                                                                  \
      float t0 = fmaf(wi1[1], h0v[1], fmaf(wi1[0], h0v[0], bia1));             \
      float t1 = fmaf(wi1[3], h0v[3], wi1[2] * h0v[2]);                        \
      float t2 = fmaf(wh1[1], h1v[1], wh1[0] * h1v[0]);                        \
      float t3 = fmaf(wh1[3], h1v[3], wh1[2] * h1v[2]);                        \
      aa1 = (t0 + t1) + (t2 + t3);                                             \
    }                                                                          \
    if (A2) {                                                                  \
      float t0 = fmaf(wi2[1], h1v[1], fmaf(wi2[0], h1v[0], bia2));             \
      float t1 = fmaf(wi2[3], h1v[3], wi2[2] * h1v[2]);                        \
      float t2 = fmaf(wh2[1], h2v[1], wh2[0] * h2v[0]);                        \
      float t3 = fmaf(wh2[3], h2v[3], wh2[2] * h2v[2]);                        \
      aa2 = (t0 + t1) + (t2 + t3);                                             \
    }                                                                          \
    if (A3) {                                                                  \
      float t0 = fmaf(wi3[1], h2v[1], fmaf(wi3[0], h2v[0], bia3));             \
      float t1 = fmaf(wi3[3], h2v[3], wi3[2] * h2v[2]);                        \
      float t2 = fmaf(wh3[1], h3v[1], wh3[0] * h3v[0]);                        \
      float t3 = fmaf(wh3[3], h3v[3], wh3[2] * h3v[2]);                        \
      aa3 = (t0 + t1) + (t2 + t3);                                             \
    }                                                                          \
    /* ---- stage 2: gate nonlinearity (kk pre-folded into weights) ---- */    \
    float e0, e1 = 0.f, e2 = 0.f, e3 = 0.f;                                    \
    e0 = __builtin_amdgcn_exp2f(aa0);                                          \
    if (A1) e1 = __builtin_amdgcn_exp2f(aa1);                                  \
    if (A2) e2 = __builtin_amdgcn_exp2f(aa2);                                  \
    if (A3) e3 = __builtin_amdgcn_exp2f(aa3);                                  \
    float r0, r1 = 0.f, r2 = 0.f, r3 = 0.f;                                    \
    r0 = __builtin_amdgcn_rcpf(1.0f + e0);                                     \
    if (A1) r1 = __builtin_amdgcn_rcpf(1.0f + e1);                             \
    if (A2) r2 = __builtin_amdgcn_rcpf(1.0f + e2);                             \
    if (A3) r3 = __builtin_amdgcn_rcpf(1.0f + e3);                             \
    float g0 = fmaf(mm, r0, dd);                                               \
    float g1 = A1 ? fmaf(mm, r1, dd) : 0.f;                                    \
    float g2 = A2 ? fmaf(mm, r2, dd) : 0.f;                                    \
    float g3 = A3 ? fmaf(mm, r3, dd) : 0.f;                                    \
    /* ---- stage 3: quad gate gather: p = act * cross(act) puts i*g on */     \
    /* the ty=0 lane; broadcast p, f, o ---- */                                \
    float q0 = g0 * dppmov<0x4E>(g0);                                          \
    float q1 = A1 ? g1 * dppmov<0x4E>(g1) : 0.f;                               \
    float q2 = A2 ? g2 * dppmov<0x4E>(g2) : 0.f;                               \
    float q3 = A3 ? g3 * dppmov<0x4E>(g3) : 0.f;                               \
    float pig0 = dppmov<0x00>(q0), gf0 = dppmov<0x55>(g0),                     \
          go0 = dppmov<0xFF>(g0);                                              \
    float pig1 = 0.f, gf1 = 0.f, go1 = 0.f;                                    \
    float pig2 = 0.f, gf2 = 0.f, go2 = 0.f;                                    \
    float pig3 = 0.f, gf3 = 0.f, go3 = 0.f;                                    \
    if (A1) {                                                                  \
      pig1 = dppmov<0x00>(q1);                                                 \
      gf1 = dppmov<0x55>(g1);                                                  \
      go1 = dppmov<0xFF>(g1);                                                  \
    }                                                                          \
    if (A2) {                                                                  \
      pig2 = dppmov<0x00>(q2);                                                 \
      gf2 = dppmov<0x55>(g2);                                                  \
      go2 = dppmov<0xFF>(g2);                                                  \
    }                                                                          \
    if (A3) {                                                                  \
      pig3 = dppmov<0x00>(q3);                                                 \
      gf3 = dppmov<0x55>(g3);                                                  \
      go3 = dppmov<0xFF>(g3);                                                  \
    }                                                                          \
    /* ---- stage 4: cell update ---- */                                       \
    c0 = fmaf(gf0, c0, pig0);                                                  \
    if (A1) c1 = fmaf(gf1, c1, pig1);                                          \
    if (A2) c2 = fmaf(gf2, c2, pig2);                                          \
    if (A3) c3 = fmaf(gf3, c3, pig3);                                          \
    /* ---- stage 5: tanh(c) and h ---- */                                     \
    float te0, te1 = 0.f, te2 = 0.f, te3 = 0.f;                                \
    te0 = __builtin_amdgcn_exp2f(c0 * KT);                                     \
    if (A1) te1 = __builtin_amdgcn_exp2f(c1 * KT);                             \
    if (A2) te2 = __builtin_amdgcn_exp2f(c2 * KT);                             \
    if (A3) te3 = __builtin_amdgcn_exp2f(c3 * KT);                             \
    float tr0, tr1 = 0.f, tr2 = 0.f, tr3 = 0.f;                                \
    tr0 = __builtin_amdgcn_rcpf(1.0f + te0);                                   \
    if (A1) tr1 = __builtin_amdgcn_rcpf(1.0f + te1);                           \
    if (A2) tr2 = __builtin_amdgcn_rcpf(1.0f + te2);                           \
    if (A3) tr3 = __builtin_amdgcn_rcpf(1.0f + te3);                           \
    float hh0 = go0 * fmaf(2.0f, tr0, -1.0f);                                  \
    float hh1 = A1 ? go1 * fmaf(2.0f, tr1, -1.0f) : 0.f;                       \
    float hh2 = A2 ? go2 * fmaf(2.0f, tr2, -1.0f) : 0.f;                       \
    float hh3 = A3 ? go3 * fmaf(2.0f, tr3, -1.0f) : 0.f;                       \
    /* ---- stage 6: distribute h across the row (state write) ---- */         \
    h0v[0] = hh0;                                                              \
    h0v[1] = dppmov<0x124>(hh0);                                               \
    h0v[2] = dppmov<0x128>(hh0);                                               \
    h0v[3] = dppmov<0x12C>(hh0);                                               \
    if (A1) {                                                                  \
      h1v[0] = hh1;                                                            \
      h1v[1] = dppmov<0x124>(hh1);                                             \
      h1v[2] = dppmov<0x128>(hh1);                                             \
      h1v[3] = dppmov<0x12C>(hh1);                                             \
    }                                                                          \
    if (A2) {                                                                  \
      h2v[0] = hh2;                                                            \
      h2v[1] = dppmov<0x124>(hh2);                                             \
      h2v[2] = dppmov<0x128>(hh2);                                             \
      h2v[3] = dppmov<0x12C>(hh2);                                             \
    }                                                                          \
    if (A3) {                                                                  \
      h3v[0] = hh3;                                                            \
      h3v[1] = dppmov<0x124>(hh3);                                             \
      h3v[2] = dppmov<0x128>(hh3);                                             \
      h3v[3] = dppmov<0x12C>(hh3);                                             \
      if (ST) {                                                                \
        float y = fmaf(wo[0], h3v[0],                                          \
                       fmaf(wo[1], h3v[1],                                     \
                            fmaf(wo[2], h3v[2], fmaf(wo[3], h3v[3], bo))));    \
        if (G == 0) out[(TAU - 3) * B_SZ + bidx] = y;                          \
      }                                                                        \
    }                                                                          \
  } while (0)

__global__ void __launch_bounds__(64, 1)
    lstm_kernel(const float *__restrict__ x, const float *__restrict__ Wih0,
                const float *__restrict__ Whh0, const float *__restrict__ bih0,
                const float *__restrict__ bhh0, const float *__restrict__ Wihr,
                const float *__restrict__ Whhr, const float *__restrict__ bihr,
                const float *__restrict__ bhhr, const float *__restrict__ Wout,
                const float *__restrict__ bout, float *__restrict__ out) {
  const int lane = threadIdx.x & 63;
  const int G = lane & 15;            // gate slot: j*4 + ty
  const int ty = G & 3;               // gate type: 0=i 1=f 2=g 3=o
  const int j = G >> 2;               // hidden unit owned by this quad
  const int bidx = blockIdx.x * 4 + (lane >> 4);  // batch element
  const int row = ty * 4 + j;         // PyTorch weight row = type*H + j

  const float KT = -2.8853900817779268f;  // -2*log2(e), for tanh via exp2

  // ---- detect ROW_ROR direction (init-only, direction-proof) ----
  float pr = dppmov<0x124>((float)j);
  const int s = (((int)pr) - j) & 3;
  int rix[4] = {j, (j + s) & 3, (j + 2) & 3, (j + 3 * s) & 3};

  // per-lane activation constants: sigmoid for i,f,o; tanh for g
  const float L2E = 1.4426950408889634f;
  const float kk = (ty == 2) ? -2.0f * L2E : -L2E;
  const float mm = (ty == 2) ? 2.0f : 1.0f;
  const float dd = (ty == 2) ? -1.0f : 0.0f;

  // ---- per-lane weight rows, pre-rotated AND pre-scaled by kk ----
  float wi0[2], wh0[4], wi1[4], wh1[4], wi2[4], wh2[4], wi3[4], wh3[4];
  wi0[0] = kk * Wih0[row * 2 + 0];
  wi0[1] = kk * Wih0[row * 2 + 1];
#pragma unroll
  for (int k = 0; k < 4; ++k) {
    int rk = rix[k];
    wh0[k] = kk * Whh0[row * 4 + rk];
    wi1[k] = kk * Wihr[0 * 64 + row * 4 + rk];
    wh1[k] = kk * Whhr[0 * 64 + row * 4 + rk];
    wi2[k] = kk * Wihr[1 * 64 + row * 4 + rk];
    wh2[k] = kk * Whhr[1 * 64 + row * 4 + rk];
    wi3[k] = kk * Wihr[2 * 64 + row * 4 + rk];
    wh3[k] = kk * Whhr[2 * 64 + row * 4 + rk];
  }
  const float bia0 = kk * (bih0[row] + bhh0[row]);
  const float bia1 = kk * (bihr[0 * 16 + row] + bhhr[0 * 16 + row]);
  const float bia2 = kk * (bihr[1 * 16 + row] + bhhr[1 * 16 + row]);
  const float bia3 = kk * (bihr[2 * 16 + row] + bhhr[2 * 16 + row]);
  float wo[4];
#pragma unroll
  for (int k = 0; k < 4; ++k) wo[k] = Wout[rix[k]];
  const float bo = bout[0];

  // ---- recurrent state (hv arrays in rotated order) ----
  float h0v[4] = {0, 0, 0, 0}, h1v[4] = {0, 0, 0, 0}, h2v[4] = {0, 0, 0, 0},
        h3v[4] = {0, 0, 0, 0};
  float c0 = 0, c1 = 0, c2 = 0, c3 = 0;

  const float2 *__restrict__ px = (const float2 *)x;  // [S*B] float2 (IN=2)

  // ---- warm-up: fill the 4-deep layer pipeline (ticks 0..2) ----
  {
    float2 xv = px[0 * B_SZ + bidx];
    TICK(false, false, false, false, xv.x, xv.y, 0);
    xv = px[1 * B_SZ + bidx];
    TICK(true, false, false, false, xv.x, xv.y, 1);
    xv = px[2 * B_SZ + bidx];
    TICK(true, true, false, false, xv.x, xv.y, 2);
  }

  // ---- x prefetch buffer: 8 ticks ahead ----
  float2 xq[8];
#pragma unroll
  for (int u = 0; u < 8; ++u) xq[u] = px[(3 + u) * B_SZ + bidx];

  // ---- main loop: ticks 3..2050 (2048 ticks = 256 x 8) ----
  for (int it = 0; it < 256; ++it) {
    const int tau0 = 3 + it * 8;
#pragma unroll
    for (int u = 0; u < 8; ++u) {
      const int tau = tau0 + u;
      float2 xv = xq[u];
      int tn = tau + 8;                    // prefetch (clamped; drain values
      if (tn > S_LEN - 1) tn = S_LEN - 1;  // never reach a stored y)
      xq[u] = px[tn * B_SZ + bidx];
      TICK(true, true, true, true, xv.x, xv.y, tau);
    }
  }
}

extern "C" void kernel_launch(void *const *d_in, const int *in_sizes, int n_in,
                              void *d_out, int out_size, void *d_ws,
                              size_t ws_size, hipStream_t stream) {
  (void)in_sizes;
  (void)n_in;
  (void)out_size;
  (void)d_ws;
  (void)ws_size;
  const float *x = (const float *)d_in[0];
  const float *Wih0 = (const float *)d_in[1];
  const float *Whh0 = (const float *)d_in[2];
  const float *bih0 = (const float *)d_in[3];
  const float *bhh0 = (const float *)d_in[4];
  const float *Wihr = (const float *)d_in[5];
  const float *Whhr = (const float *)d_in[6];
  const float *bihr = (const float *)d_in[7];
  const float *bhhr = (const float *)d_in[8];
  const float *Wout = (const float *)d_in[9];
  const float *bout = (const float *)d_in[10];
  lstm_kernel<<<dim3(512), dim3(64), 0, stream>>>(
      x, Wih0, Whh0, bih0, bhh0, Wihr, Whhr, bihr, bhhr, Wout, bout,
      (float *)d_out);
}

// Round 5
// 453.638 us; speedup vs baseline: 1.9623x; 1.4318x over previous
//
#include <hip/hip_runtime.h>

#define S_LEN 2048
#define B_SZ 2048

// Pure-VALU DPP move (no LDS pipe).
template <int CTRL>
__device__ __forceinline__ float dppmov(float v) {
  int r = __builtin_amdgcn_update_dpp(0, __builtin_bit_cast(int, v), CTRL, 0xF,
                                      0xF, true);
  return __builtin_bit_cast(float, r);
}

// readlane: broadcast lane L's value to an SGPR (no memory counter involved).
__device__ __forceinline__ float rlane(float v, int l) {
  return __builtin_bit_cast(
      float, __builtin_amdgcn_readlane(__builtin_bit_cast(int, v), l));
}

// Decomposition: wave = 1 batch element. Row r (16 lanes) = layer r.
// Within a row: G = lane&15 = j*4 + ty (j = hidden unit = quad, ty = gate
// type 0=i 1=f 2=g 3=o). Gate gather: quad_perm DPP. Own-layer h distribution:
// row_ror DPP (hv[k] = h_{(j+s*k)&3}, wh pre-rotated). Inter-layer transfer:
// ty==0 lanes publish h_j to LDS slot[row][j] (other lanes write a trash bin
// so the ds_write needs no exec masking); every lane reads slot[row-1] as one
// b128 at END of tick, consumed next tick (1 tick of slack hides DS latency).
// Layer l at tick tau processes t = tau - l. TT is the already-shifted store
// index (t for layer 3).
#define TICK(ST, XVX, XVY, TT)                                                 \
  do {                                                                         \
    float i0 = is_row0 ? (XVX) : hin[0];                                       \
    float i1 = is_row0 ? (XVY) : hin[1];                                       \
    float t2 = fmaf(wh[1], hv[1], wh[0] * hv[0]);                              \
    float t3 = fmaf(wh[3], hv[3], wh[2] * hv[2]);                              \
    float t0 = fmaf(wi[1], i1, fmaf(wi[0], i0, bias));                         \
    float t1 = fmaf(wi[3], hin[3], wi[2] * hin[2]);                            \
    float a = (t0 + t1) + (t2 + t3);                                           \
    float e = __builtin_amdgcn_exp2f(a);                                       \
    float r = __builtin_amdgcn_rcpf(1.0f + e);                                 \
    float g = fmaf(mm, r, dd);                                                 \
    float q = g * dppmov<0x4E>(g); /* i*g lands on ty0 lane */                 \
    float pig = dppmov<0x00>(q);                                               \
    float gf = dppmov<0x55>(g);                                                \
    float go = dppmov<0xFF>(g);                                                \
    c = fmaf(gf, c, pig);                                                      \
    float te = __builtin_amdgcn_exp2f(c * KT);                                 \
    float tr = __builtin_amdgcn_rcpf(1.0f + te);                               \
    float hh = go * fmaf(2.0f, tr, -1.0f);                                     \
    hv[0] = hh;                                                                \
    hv[1] = dppmov<0x124>(hh);                                                 \
    hv[2] = dppmov<0x128>(hh);                                                 \
    hv[3] = dppmov<0x12C>(hh);                                                 \
    slotf[wr_off] = hh; /* unpredicated: non-ty0 lanes hit trash bin */        \
    __builtin_amdgcn_wave_barrier();                                           \
    float4 nh = slot4[rd_slot];                                                \
    hin[0] = nh.x;                                                             \
    hin[1] = nh.y;                                                             \
    hin[2] = nh.z;                                                             \
    hin[3] = nh.w;                                                             \
    if (ST) {                                                                  \
      float y = fmaf(                                                          \
          wo[0], hv[0],                                                        \
          fmaf(wo[1], hv[1], fmaf(wo[2], hv[2], fmaf(wo[3], hv[3], bo))));     \
      if (do_store) out[(TT)*B_SZ + bidx] = y;                                 \
    }                                                                          \
  } while (0)

__global__ void __launch_bounds__(64, 2)
    lstm_kernel(const float *__restrict__ x, const float *__restrict__ Wih0,
                const float *__restrict__ Whh0, const float *__restrict__ bih0,
                const float *__restrict__ bhh0, const float *__restrict__ Wihr,
                const float *__restrict__ Whhr, const float *__restrict__ bihr,
                const float *__restrict__ bhhr, const float *__restrict__ Wout,
                const float *__restrict__ bout, float *__restrict__ out) {
  // 16 real slots (layer x hidden) + 64-float trash bin (one per lane)
  __shared__ __align__(16) float slotf[80];
  float4 *slot4 = (float4 *)slotf;

  const int lane = threadIdx.x & 63;
  const int ty = lane & 3;             // gate type
  const int j = (lane >> 2) & 3;       // hidden unit (quad)
  const int row = lane >> 4;           // layer
  const int bidx = blockIdx.x;         // batch element (1 per wave)
  const int wrow = ty * 4 + j;         // PyTorch weight row = type*H + j
  const bool is_row0 = (row == 0);
  const bool do_store = (lane == 48);  // layer 3, G==0
  const int wr_off = (ty == 0) ? ((row << 2) | j) : (16 + lane);
  const int rd_slot = (row + 3) & 3;   // layer row-1's slot (row0: ignored)

  // zero-init LDS so pre-real garbage stays finite
  slotf[lane] = 0.0f;
  slotf[16 + lane] = 0.0f;
  __builtin_amdgcn_wave_barrier();

  // ---- detect ROW_ROR direction (init-only, direction-proof) ----
  float pr = dppmov<0x124>((float)j);
  const int s = (((int)pr) - j) & 3;
  int rix[4] = {j, (j + s) & 3, (j + 2) & 3, (j + 3 * s) & 3};

  // per-lane activation constants: sigmoid for i,f,o; tanh for g
  const float L2E = 1.4426950408889634f;
  const float kk = (ty == 2) ? -2.0f * L2E : -L2E;
  const float mm = (ty == 2) ? 2.0f : 1.0f;
  const float dd = (ty == 2) ? -1.0f : 0.0f;
  const float KT = -2.8853900817779268f;  // -2*log2(e)

  // ---- this layer's weight row; wi natural order (hin arrives natural),
  //      wh pre-rotated; all pre-scaled by kk ----
  float wi[4], wh[4], bias;
  if (row == 0) {
    wi[0] = kk * Wih0[wrow * 2 + 0];
    wi[1] = kk * Wih0[wrow * 2 + 1];
    wi[2] = 0.0f;
    wi[3] = 0.0f;
#pragma unroll
    for (int k = 0; k < 4; ++k) wh[k] = kk * Whh0[wrow * 4 + rix[k]];
    bias = kk * (bih0[wrow] + bhh0[wrow]);
  } else {
    const int l = row - 1;
#pragma unroll
    for (int k = 0; k < 4; ++k) {
      wi[k] = kk * Wihr[l * 64 + wrow * 4 + k];
      wh[k] = kk * Whhr[l * 64 + wrow * 4 + rix[k]];
    }
    bias = kk * (bihr[l * 16 + wrow] + bhhr[l * 16 + wrow]);
  }
  float wo[4];
#pragma unroll
  for (int k = 0; k < 4; ++k) wo[k] = Wout[rix[k]];
  const float bo = bout[0];

  // ---- recurrent state ----
  float hv[4] = {0, 0, 0, 0};   // own layer h (rotated order)
  float hin[4] = {0, 0, 0, 0};  // prev layer h (natural order)
  float c = 0.0f;

  const float2 *__restrict__ px = (const float2 *)x;  // [S*B] float2 (IN=2)

  // divergent x loader: lane (lane&7) fetches tick base+(lane&7); a single
  // global_load_dwordx2 per 8 ticks, vmcnt domain (no lgkmcnt pollution).
  const int l8 = lane & 7;
  auto ldx = [&](int base) -> float2 {
    int t = base + l8;
    if (t > S_LEN - 1) t = S_LEN - 1;  // clamp: drain values never stored
    return px[t * B_SZ + bidx];
  };

  // ---- warm-up ticks 0..2 (plain loads; one-time) ----
  {
    float2 xv = px[0 * B_SZ + bidx];
    TICK(false, xv.x, xv.y, 0);
    if (row > 0) { c = 0; hv[0] = hv[1] = hv[2] = hv[3] = 0; }
    xv = px[1 * B_SZ + bidx];
    TICK(false, xv.x, xv.y, 0);
    if (row > 1) { c = 0; hv[0] = hv[1] = hv[2] = hv[3] = 0; }
    xv = px[2 * B_SZ + bidx];
    TICK(false, xv.x, xv.y, 0);
    if (row > 2) { c = 0; hv[0] = hv[1] = hv[2] = hv[3] = 0; }
  }

  // ---- x double-buffer: 8..16 ticks ahead ----
  float2 xa = ldx(3);   // ticks 3..10
  float2 xb = ldx(11);  // ticks 11..18

  // ---- main loop: ticks 3..2050 (2048 = 256 x 8) ----
  for (int it = 0; it < 256; ++it) {
    float2 xn = ldx(19 + it * 8);  // refill, consumed 16 ticks later
#pragma unroll
    for (int u = 0; u < 8; ++u) {
      const int tt = it * 8 + u;  // = tau - 3, the store timestep
      float xvx = rlane(xa.x, u);
      float xvy = rlane(xa.y, u);
      TICK(true, xvx, xvy, tt);
    }
    xa = xb;
    xb = xn;
  }
}

extern "C" void kernel_launch(void *const *d_in, const int *in_sizes, int n_in,
                              void *d_out, int out_size, void *d_ws,
                              size_t ws_size, hipStream_t stream) {
  (void)in_sizes;
  (void)n_in;
  (void)out_size;
  (void)d_ws;
  (void)ws_size;
  const float *x = (const float *)d_in[0];
  const float *Wih0 = (const float *)d_in[1];
  const float *Whh0 = (const float *)d_in[2];
  const float *bih0 = (const float *)d_in[3];
  const float *bhh0 = (const float *)d_in[4];
  const float *Wihr = (const float *)d_in[5];
  const float *Whhr = (const float *)d_in[6];
  const float *bihr = (const float *)d_in[7];
  const float *bhhr = (const float *)d_in[8];
  const float *Wout = (const float *)d_in[9];
  const float *bout = (const float *)d_in[10];
  lstm_kernel<<<dim3(B_SZ), dim3(64), 0, stream>>>(
      x, Wih0, Whh0, bih0, bhh0, Wihr, Whhr, bihr, bhhr, Wout, bout,
      (float *)d_out);
}